// Round 1
// baseline (2297.034 us; speedup 1.0000x reference)
//
#include <hip/hip_runtime.h>
#include <math.h>

#define BATCH   512
#define TSTEPS  3600
#define H       64
#define CHUNK   180
#define NCHUNK  (TSTEPS / CHUNK)   // 20
#define CLASSES 5

__device__ __forceinline__ float fast_sigmoid(float x) {
    x = fminf(fmaxf(x, -30.0f), 30.0f);
    float e = __expf(-x);
    return __builtin_amdgcn_rcpf(1.0f + e);
}

__device__ __forceinline__ float fast_tanh(float x) {
    float a = fabsf(x);
    float t = __expf(-2.0f * a);                    // in (0, 1], never overflows
    float r = (1.0f - t) * __builtin_amdgcn_rcpf(1.0f + t);
    return copysignf(r, x);
}

// One block per batch element. 3 waves: wave g computes gate g's recurrent
// dot products (row g*64+lane of w_hh, held in 64 VGPRs). h is broadcast from
// a per-wave LDS copy (wave-uniform float4 reads -> HW broadcast, no
// conflicts, no cross-wave dependency). Gate pre-activations go through a
// ping-pong LDS buffer; ONE __syncthreads per timestep. Phase 2 (gate
// nonlinearity + h update) is computed redundantly by all 3 waves so each
// wave can refresh its own h copy without a second barrier.
__global__ __launch_bounds__(192, 2) void gru_fused_kernel(
    const float* __restrict__ x,      // [B, T, 1]
    const float* __restrict__ w_ih,   // [192, 1]
    const float* __restrict__ w_hh,   // [192, 64]
    const float* __restrict__ b_ih,   // [192]
    const float* __restrict__ b_hh,   // [192]
    const float* __restrict__ w_head, // [5, 64]
    const float* __restrict__ b_head, // [5]
    float* __restrict__ out)          // [B, 5]
{
    __shared__ __align__(16) float hbuf[3][H];   // per-wave h copy
    __shared__ float gbuf[2][3][H];              // ping-pong gate pre-acts
    __shared__ float xl[CHUNK];

    const int tid  = threadIdx.x;
    const int wv   = tid >> 6;     // 0=r, 1=z, 2=n
    const int lane = tid & 63;
    const int b    = blockIdx.x;

    // Recurrent weight row for this thread, kept in registers.
    const int row = wv * H + lane;
    float w[H];
#pragma unroll
    for (int j = 0; j < H; ++j) w[j] = w_hh[row * H + j];

    // Per-lane (index i) parameters needed by the redundant phase-2.
    const float wih_r = w_ih[lane], wih_z = w_ih[H + lane], wih_n = w_ih[2 * H + lane];
    const float bih_r = b_ih[lane], bih_z = b_ih[H + lane], bih_n = b_ih[2 * H + lane];
    const float bhh_r = b_hh[lane], bhh_z = b_hh[H + lane], bhh_n = b_hh[2 * H + lane];

    float h_reg = 0.0f;            // h_i, identical across the 3 waves
    hbuf[wv][lane] = 0.0f;         // own-wave copy; same-wave ordering only

    int p = 0;
    const float* xb = x + (size_t)b * TSTEPS;

    for (int c = 0; c < NCHUNK; ++c) {
        if (tid < CHUNK) xl[tid] = xb[c * CHUNK + tid];
        __syncthreads();           // xl visible; also seals previous epoch

        for (int tt = 0; tt < CHUNK; ++tt) {
            // ---- phase 1: recurrent dot from OWN wave's h copy ----
            const float* hb = hbuf[wv];
            float a0 = 0.f, a1 = 0.f, a2 = 0.f, a3 = 0.f;
#pragma unroll
            for (int j4 = 0; j4 < H / 4; ++j4) {
                float4 h4 = *(const float4*)(hb + 4 * j4);   // wave-uniform broadcast
                a0 = fmaf(w[4 * j4 + 0], h4.x, a0);
                a1 = fmaf(w[4 * j4 + 1], h4.y, a1);
                a2 = fmaf(w[4 * j4 + 2], h4.z, a2);
                a3 = fmaf(w[4 * j4 + 3], h4.w, a3);
            }
            const float dot = (a0 + a1) + (a2 + a3);
            const float xt  = xl[tt];          // into reg: phase 2 won't touch xl
            gbuf[p][wv][lane] = dot;

            __syncthreads();                   // the ONE barrier per step

            // ---- phase 2: redundant on all waves ----
            const float gr = gbuf[p][0][lane];
            const float gz = gbuf[p][1][lane];
            const float gn = gbuf[p][2][lane];
            const float r  = fast_sigmoid(fmaf(xt, wih_r, bih_r) + gr + bhh_r);
            const float z  = fast_sigmoid(fmaf(xt, wih_z, bih_z) + gz + bhh_z);
            const float n  = fast_tanh(fmaf(xt, wih_n, bih_n) + r * (gn + bhh_n));
            h_reg = (1.0f - z) * n + z * h_reg;
            hbuf[wv][lane] = h_reg;            // own copy; next phase-1 is same-wave
            p ^= 1;
        }
    }

    // ---- head: out[b][c] = w_head[c,:] . h + b_head[c], wave 0 only ----
    if (wv == 0) {
#pragma unroll
        for (int cc = 0; cc < CLASSES; ++cc) {
            float v = h_reg * w_head[cc * H + lane];
#pragma unroll
            for (int off = 32; off > 0; off >>= 1)
                v += __shfl_down(v, off, 64);
            if (lane == 0) out[b * CLASSES + cc] = v + b_head[cc];
        }
    }
}

extern "C" void kernel_launch(void* const* d_in, const int* in_sizes, int n_in,
                              void* d_out, int out_size, void* d_ws, size_t ws_size,
                              hipStream_t stream) {
    const float* x      = (const float*)d_in[0];
    const float* w_ih   = (const float*)d_in[1];
    const float* w_hh   = (const float*)d_in[2];
    const float* b_ih   = (const float*)d_in[3];
    const float* b_hh   = (const float*)d_in[4];
    const float* w_head = (const float*)d_in[5];
    const float* b_head = (const float*)d_in[6];
    float* out = (float*)d_out;

    gru_fused_kernel<<<BATCH, 192, 0, stream>>>(x, w_ih, w_hh, b_ih, b_hh,
                                                w_head, b_head, out);
}

// Round 2
// 2039.067 us; speedup vs baseline: 1.1265x; 1.1265x over previous
//
#include <hip/hip_runtime.h>
#include <math.h>

#define BATCH   512
#define TSTEPS  3600
#define H       64
#define CHUNK   180
#define NCHUNK  (TSTEPS / CHUNK)   // 20
#define CLASSES 5

__device__ __forceinline__ float fast_sigmoid(float x) {
    x = fminf(fmaxf(x, -30.0f), 30.0f);
    float e = __expf(-x);
    return __builtin_amdgcn_rcpf(1.0f + e);
}

__device__ __forceinline__ float fast_tanh(float x) {
    float a = fabsf(x);
    float t = __expf(-2.0f * a);                    // in (0, 1], never overflows
    float r = (1.0f - t) * __builtin_amdgcn_rcpf(1.0f + t);
    return copysignf(r, x);
}

// ONE WAVE per batch element: fully wave-synchronous recurrence, zero
// __syncthreads in the 3600-step loop. Lane i owns h_i and all three
// recurrent rows {i, 64+i, 128+i} of w_hh (192 floats/lane, resident in the
// unified VGPR/AGPR file via __launch_bounds__(64,1)). Per step:
//   1 ds_write_b32 (publish h_i) -> 16 wave-uniform ds_read_b128 (broadcast
//   h, conflict-free) -> 192 fmac (12 independent accumulators) -> in-lane
//   phase 2 (no redundancy, no cross-wave traffic).
// The only waits are compiler-inserted lgkmcnt on the LDS write->read pair.
__global__ __launch_bounds__(64, 1) void gru_wave_kernel(
    const float* __restrict__ x,      // [B, T, 1]
    const float* __restrict__ w_ih,   // [192, 1]
    const float* __restrict__ w_hh,   // [192, 64]
    const float* __restrict__ b_ih,   // [192]
    const float* __restrict__ b_hh,   // [192]
    const float* __restrict__ w_head, // [5, 64]
    const float* __restrict__ b_head, // [5]
    float* __restrict__ out)          // [B, 5]
{
    __shared__ __align__(16) float hl[H];
    __shared__ float xl[CHUNK];

    const int lane = threadIdx.x;    // block = 1 wave
    const int b    = blockIdx.x;

    // --- load recurrent weights: 3 rows x 64 = 192 floats per lane ---
    float w[3][H];
#pragma unroll
    for (int g = 0; g < 3; ++g) {
        const float4* wrow = (const float4*)(w_hh + (g * H + lane) * H);
#pragma unroll
        for (int j4 = 0; j4 < H / 4; ++j4) {
            float4 v = wrow[j4];
            w[g][4 * j4 + 0] = v.x;
            w[g][4 * j4 + 1] = v.y;
            w[g][4 * j4 + 2] = v.z;
            w[g][4 * j4 + 3] = v.w;
        }
    }

    const float wih_r = w_ih[lane], wih_z = w_ih[H + lane], wih_n = w_ih[2 * H + lane];
    const float bih_r = b_ih[lane], bih_z = b_ih[H + lane], bih_n = b_ih[2 * H + lane];
    const float bhh_r = b_hh[lane], bhh_z = b_hh[H + lane], bhh_n = b_hh[2 * H + lane];

    float h_reg = 0.0f;
    const float* xb = x + (size_t)b * TSTEPS;

    for (int c = 0; c < NCHUNK; ++c) {
        // stage this chunk of x (wave-synchronous; lgkmcnt guards the reads)
#pragma unroll
        for (int k = 0; k < 3; ++k) {
            int idx = lane + 64 * k;
            if (idx < CHUNK) xl[idx] = xb[c * CHUNK + idx];
        }

        for (int tt = 0; tt < CHUNK; ++tt) {
            // publish h_i, then broadcast-read the full h vector
            hl[lane] = h_reg;

            float ar0 = bhh_r, ar1 = 0.f, ar2 = 0.f, ar3 = 0.f;
            float az0 = bhh_z, az1 = 0.f, az2 = 0.f, az3 = 0.f;
            float an0 = bhh_n, an1 = 0.f, an2 = 0.f, an3 = 0.f;
#pragma unroll
            for (int j4 = 0; j4 < H / 4; ++j4) {
                float4 h4 = *(const float4*)(hl + 4 * j4);   // wave-uniform broadcast
                ar0 = fmaf(w[0][4 * j4 + 0], h4.x, ar0);
                ar1 = fmaf(w[0][4 * j4 + 1], h4.y, ar1);
                ar2 = fmaf(w[0][4 * j4 + 2], h4.z, ar2);
                ar3 = fmaf(w[0][4 * j4 + 3], h4.w, ar3);
                az0 = fmaf(w[1][4 * j4 + 0], h4.x, az0);
                az1 = fmaf(w[1][4 * j4 + 1], h4.y, az1);
                az2 = fmaf(w[1][4 * j4 + 2], h4.z, az2);
                az3 = fmaf(w[1][4 * j4 + 3], h4.w, az3);
                an0 = fmaf(w[2][4 * j4 + 0], h4.x, an0);
                an1 = fmaf(w[2][4 * j4 + 1], h4.y, an1);
                an2 = fmaf(w[2][4 * j4 + 2], h4.z, an2);
                an3 = fmaf(w[2][4 * j4 + 3], h4.w, an3);
            }
            const float dr = (ar0 + ar1) + (ar2 + ar3);
            const float dz = (az0 + az1) + (az2 + az3);
            const float dn = (an0 + an1) + (an2 + an3);

            const float xt = xl[tt];                         // uniform broadcast
            const float r  = fast_sigmoid(fmaf(xt, wih_r, bih_r) + dr);
            const float z  = fast_sigmoid(fmaf(xt, wih_z, bih_z) + dz);
            const float n  = fast_tanh(fmaf(xt, wih_n, bih_n) + r * dn);
            h_reg = (1.0f - z) * n + z * h_reg;
        }
    }

    // ---- head: out[b][c] = w_head[c,:] . h + b_head[c] ----
#pragma unroll
    for (int cc = 0; cc < CLASSES; ++cc) {
        float v = h_reg * w_head[cc * H + lane];
#pragma unroll
        for (int off = 32; off > 0; off >>= 1)
            v += __shfl_down(v, off, 64);
        if (lane == 0) out[b * CLASSES + cc] = v + b_head[cc];
    }
}

extern "C" void kernel_launch(void* const* d_in, const int* in_sizes, int n_in,
                              void* d_out, int out_size, void* d_ws, size_t ws_size,
                              hipStream_t stream) {
    const float* x      = (const float*)d_in[0];
    const float* w_ih   = (const float*)d_in[1];
    const float* w_hh   = (const float*)d_in[2];
    const float* b_ih   = (const float*)d_in[3];
    const float* b_hh   = (const float*)d_in[4];
    const float* w_head = (const float*)d_in[5];
    const float* b_head = (const float*)d_in[6];
    float* out = (float*)d_out;

    gru_wave_kernel<<<BATCH, 64, 0, stream>>>(x, w_ih, w_hh, b_ih, b_hh,
                                              w_head, b_head, out);
}